// Round 6
// baseline (177.547 us; speedup 1.0000x reference)
//
#include <hip/hip_runtime.h>
#include <math.h>

#define NIMG 32
#define CDIM 256
#define KCL  64
#define SPIX 4096

// ---------------- K0: transpose conv_w (K x C) -> wT (C x K) ----------------
__global__ __launch_bounds__(256) void k_wt(const float* __restrict__ w, float* __restrict__ wT) {
    int g = blockIdx.x * 256 + threadIdx.x;   // g = k*CDIM + c
    if (g < KCL * CDIM) {
        int k = g / CDIM, c = g % CDIM;
        wT[c * KCL + k] = w[g];
    }
}

#define FMA8(P, XV) \
    acc[P*8+0] = fmaf(w0.x, XV, acc[P*8+0]); acc[P*8+1] = fmaf(w0.y, XV, acc[P*8+1]); \
    acc[P*8+2] = fmaf(w0.z, XV, acc[P*8+2]); acc[P*8+3] = fmaf(w0.w, XV, acc[P*8+3]); \
    acc[P*8+4] = fmaf(w1.x, XV, acc[P*8+4]); acc[P*8+5] = fmaf(w1.y, XV, acc[P*8+5]); \
    acc[P*8+6] = fmaf(w1.z, XV, acc[P*8+6]); acc[P*8+7] = fmaf(w1.w, XV, acc[P*8+7]);

// ---------------- K1: fused norm + logits + softmax + asum ------------------
// grid 512 = (n, 16 groups of 256 px), 512 threads = 8 waves.
// Thread tile: 4 px (lane quad) x 8 k (wave slice). x staged in LDS chunks of
// 64 c (coalesced float4, VMEM latency amortized 8x per chunk, sumsq fused).
// Inner loop: 1 contiguous ds_read_b128 + batched 32B s_load + 32 FMA.
// Rounds 1-5 kept a per-lane VMEM load in the inner loop -> latency-bound
// (VALUBusy 18-30%). This removes it.
__global__ __launch_bounds__(512, 4) void k_logits(const float* __restrict__ x,
                                                   const float* __restrict__ wT,
                                                   const float* __restrict__ b,
                                                   float* __restrict__ aT,
                                                   float* __restrict__ inv_norm,
                                                   float* __restrict__ asum_part) {
    int blk = blockIdx.x;
    int n = blk >> 4, g = blk & 15;
    int s0 = g * 256;
    int tid = threadIdx.x;
    int wv = tid >> 6, l = tid & 63;
    int wvu = __builtin_amdgcn_readfirstlane(wv);

    __shared__ float xs[64 * 256];     // [c-in-chunk][px], rows contiguous
    __shared__ float4 red[8 * 64];     // [wave][px-quad]

    float acc[32];
    #pragma unroll
    for (int i = 0; i < 32; i++) acc[i] = 0.f;
    float4 sq = {0.f, 0.f, 0.f, 0.f};

    for (int t = 0; t < 4; t++) {
        if (t) __syncthreads();
        // stage chunk: wave wv loads rows 8wv..8wv+8; lane -> px quad (float4)
        #pragma unroll
        for (int i = 0; i < 8; i++) {
            int c = wvu * 8 + i;
            float4 xv = *(const float4*)(x + ((size_t)(n * CDIM + t * 64 + c)) * SPIX + s0 + 4 * l);
            sq.x = fmaf(xv.x, xv.x, sq.x);
            sq.y = fmaf(xv.y, xv.y, sq.y);
            sq.z = fmaf(xv.z, xv.z, sq.z);
            sq.w = fmaf(xv.w, xv.w, sq.w);
            *(float4*)(xs + c * 256 + 4 * l) = xv;   // contiguous b128: conflict-free
        }
        __syncthreads();
        const float* wrow = wT + (size_t)(t * 64) * KCL + 8 * wvu;   // uniform
        #pragma unroll 8
        for (int cc = 0; cc < 64; cc++) {
            const float4* wp = (const float4*)(wrow + (size_t)cc * KCL);
            float4 w0 = wp[0], w1 = wp[1];                           // s_load, batched x8
            float4 xq = *(const float4*)(xs + cc * 256 + 4 * l);     // contiguous b128
            FMA8(0, xq.x) FMA8(1, xq.y) FMA8(2, xq.z) FMA8(3, xq.w)
        }
    }

    // ---- invn: cross-wave sumsq reduce (each wave covered 64 of 256 c) ----
    red[wv * 64 + l] = sq;
    __syncthreads();
    float4 ssq = red[l];
    #pragma unroll
    for (int i = 1; i < 8; i++) {
        float4 t4 = red[i * 64 + l];
        ssq.x += t4.x; ssq.y += t4.y; ssq.z += t4.z; ssq.w += t4.w;
    }
    float4 invn;
    invn.x = 1.f / fmaxf(sqrtf(ssq.x), 1e-12f);
    invn.y = 1.f / fmaxf(sqrtf(ssq.y), 1e-12f);
    invn.z = 1.f / fmaxf(sqrtf(ssq.z), 1e-12f);
    invn.w = 1.f / fmaxf(sqrtf(ssq.w), 1e-12f);
    if (wv == 0) *(float4*)(inv_norm + (size_t)n * SPIX + s0 + 4 * l) = invn;

    // ---- logits = acc*invn + b ----
    const float4* bp = (const float4*)(b + 8 * wvu);
    float4 b0 = bp[0], b1 = bp[1];
    float iv[4] = {invn.x, invn.y, invn.z, invn.w};
    #pragma unroll
    for (int p = 0; p < 4; p++) {
        acc[p*8+0] = fmaf(acc[p*8+0], iv[p], b0.x);
        acc[p*8+1] = fmaf(acc[p*8+1], iv[p], b0.y);
        acc[p*8+2] = fmaf(acc[p*8+2], iv[p], b0.z);
        acc[p*8+3] = fmaf(acc[p*8+3], iv[p], b0.w);
        acc[p*8+4] = fmaf(acc[p*8+4], iv[p], b1.x);
        acc[p*8+5] = fmaf(acc[p*8+5], iv[p], b1.y);
        acc[p*8+6] = fmaf(acc[p*8+6], iv[p], b1.z);
        acc[p*8+7] = fmaf(acc[p*8+7], iv[p], b1.w);
    }

    // ---- softmax over 64 k (8 k local x 8 waves) ----
    float4 m4;
    {
        float m[4];
        #pragma unroll
        for (int p = 0; p < 4; p++) {
            float mm = acc[p*8+0];
            #pragma unroll
            for (int j = 1; j < 8; j++) mm = fmaxf(mm, acc[p*8+j]);
            m[p] = mm;
        }
        m4.x = m[0]; m4.y = m[1]; m4.z = m[2]; m4.w = m[3];
    }
    __syncthreads();
    red[wv * 64 + l] = m4;
    __syncthreads();
    m4 = red[l];
    #pragma unroll
    for (int i = 1; i < 8; i++) {
        float4 t4 = red[i * 64 + l];
        m4.x = fmaxf(m4.x, t4.x); m4.y = fmaxf(m4.y, t4.y);
        m4.z = fmaxf(m4.z, t4.z); m4.w = fmaxf(m4.w, t4.w);
    }
    float mv[4] = {m4.x, m4.y, m4.z, m4.w};
    float4 s4 = {0.f, 0.f, 0.f, 0.f};
    float sv[4] = {0.f, 0.f, 0.f, 0.f};
    #pragma unroll
    for (int p = 0; p < 4; p++) {
        #pragma unroll
        for (int j = 0; j < 8; j++) {
            float e = __expf(acc[p*8+j] - mv[p]);
            acc[p*8+j] = e;
            sv[p] += e;
        }
    }
    s4.x = sv[0]; s4.y = sv[1]; s4.z = sv[2]; s4.w = sv[3];
    __syncthreads();
    red[wv * 64 + l] = s4;
    __syncthreads();
    s4 = red[l];
    #pragma unroll
    for (int i = 1; i < 8; i++) {
        float4 t4 = red[i * 64 + l];
        s4.x += t4.x; s4.y += t4.y; s4.z += t4.z; s4.w += t4.w;
    }
    float rv[4] = {1.f / s4.x, 1.f / s4.y, 1.f / s4.z, 1.f / s4.w};
    #pragma unroll
    for (int p = 0; p < 4; p++)
        #pragma unroll
        for (int j = 0; j < 8; j++) acc[p*8+j] *= rv[p];

    // ---- write a: aT[n][s][k] ----
    #pragma unroll
    for (int p = 0; p < 4; p++) {
        float4 a0 = {acc[p*8+0], acc[p*8+1], acc[p*8+2], acc[p*8+3]};
        float4 a1 = {acc[p*8+4], acc[p*8+5], acc[p*8+6], acc[p*8+7]};
        float4* dst = (float4*)(aT + ((size_t)(n * SPIX + s0 + 4 * l + p)) * KCL + 8 * wvu);
        dst[0] = a0; dst[1] = a1;
    }

    // ---- asum partials over this block's 256 px ----
    #pragma unroll
    for (int j = 0; j < 8; j++) {
        float v = acc[j] + acc[8 + j] + acc[16 + j] + acc[24 + j];
        #pragma unroll
        for (int off = 32; off > 0; off >>= 1) v += __shfl_xor(v, off, 64);
        if (l == 0) asum_part[blk * KCL + 8 * wvu + j] = v;
    }
}

#define VFMA8(Q, XV) \
    acc[Q*8+0] = fmaf(a0.x, XV, acc[Q*8+0]); acc[Q*8+1] = fmaf(a0.y, XV, acc[Q*8+1]); \
    acc[Q*8+2] = fmaf(a0.z, XV, acc[Q*8+2]); acc[Q*8+3] = fmaf(a0.w, XV, acc[Q*8+3]); \
    acc[Q*8+4] = fmaf(a1.x, XV, acc[Q*8+4]); acc[Q*8+5] = fmaf(a1.y, XV, acc[Q*8+5]); \
    acc[Q*8+6] = fmaf(a1.z, XV, acc[Q*8+6]); acc[Q*8+7] = fmaf(a1.w, XV, acc[Q*8+7]);

// ---------------- K2: vlad partials -----------------------------------------
// grid 512 = (n, 16 groups of 256 s), 512 threads. Thread tile: 4 c x 8 k.
// x^ staged per 64-s chunk as xt[s][c] (pitch 260 words -> b128 reads are
// contiguous 16B-aligned rows, conflict-free). a read as batched uniform
// s_load (32 B/iter). Same structure as k_logits.
__global__ __launch_bounds__(512, 4) void k_vlad(const float* __restrict__ x,
                                                 const float* __restrict__ inv_norm,
                                                 const float* __restrict__ aT,
                                                 float* __restrict__ vlad_part) {
    int blk = blockIdx.x;
    int n = blk >> 4, g = blk & 15;
    int tid = threadIdx.x;
    int wv = tid >> 6, l = tid & 63;
    int wvu = __builtin_amdgcn_readfirstlane(wv);

    __shared__ float xt[64 * 260];   // [s-in-chunk][c], pitch 260

    float acc[32];
    #pragma unroll
    for (int i = 0; i < 32; i++) acc[i] = 0.f;

    for (int t = 0; t < 4; t++) {
        int sc0 = g * 256 + t * 64;
        if (t) __syncthreads();
        float invs = inv_norm[(size_t)n * SPIX + sc0 + l];   // lane -> s
        // stage: wave wv covers c in [32wv, 32wv+32), 4 c per b128 write
        #pragma unroll
        for (int i = 0; i < 8; i++) {
            int c = wvu * 32 + i * 4;
            const float* xb = x + ((size_t)(n * CDIM + c)) * SPIX + sc0 + l;
            float4 xv;
            xv.x = xb[0 * SPIX] * invs;
            xv.y = xb[1 * SPIX] * invs;
            xv.z = xb[2 * SPIX] * invs;
            xv.w = xb[3 * SPIX] * invs;
            *(float4*)(xt + l * 260 + c) = xv;
        }
        __syncthreads();
        const float* ab = aT + ((size_t)(n * SPIX + sc0)) * KCL + 8 * wvu;  // uniform
        #pragma unroll 8
        for (int si = 0; si < 64; si++) {
            const float4* ap = (const float4*)(ab + (size_t)si * KCL);
            float4 a0 = ap[0], a1 = ap[1];                        // s_load, batched x8
            float4 xq = *(const float4*)(xt + si * 260 + 4 * l);  // contiguous b128
            VFMA8(0, xq.x) VFMA8(1, xq.y) VFMA8(2, xq.z) VFMA8(3, xq.w)
        }
    }
    // write vlad_part[blk][k][c]: coalesced b128 rows
    #pragma unroll
    for (int j = 0; j < 8; j++) {
        float4 v = {acc[j], acc[8 + j], acc[16 + j], acc[24 + j]};
        *(float4*)(vlad_part + ((size_t)blk * KCL + 8 * wvu + j) * CDIM + 4 * l) = v;
    }
}

// ---------------- K4: combine partials + centroid subtract + intra-norm ----
// grid 2048 = (n,k), 256 threads (c = tid)
__global__ __launch_bounds__(256) void k_combine(const float* __restrict__ vlad_part,
                                                 const float* __restrict__ asum_part,
                                                 const float* __restrict__ cent,
                                                 float* __restrict__ out,
                                                 float* __restrict__ rs) {
    int blk = blockIdx.x;          // n*64 + k
    int n = blk >> 6, k = blk & 63;
    int c = threadIdx.x;
    float v = 0.f;
    for (int j = 0; j < 16; j++)
        v += vlad_part[(((size_t)(n * 16 + j)) * KCL + k) * CDIM + c];
    float as = 0.f;
    for (int j = 0; j < 16; j++)
        as += asum_part[(n * 16 + j) * KCL + k];
    v = fmaf(-as, cent[k * CDIM + c], v);

    float t = v * v;
    #pragma unroll
    for (int off = 32; off > 0; off >>= 1) t += __shfl_xor(t, off, 64);
    __shared__ float w4[4];
    int lane = threadIdx.x & 63, wid = threadIdx.x >> 6;
    if (lane == 0) w4[wid] = t;
    __syncthreads();
    float ss = w4[0] + w4[1] + w4[2] + w4[3];
    float inv = 1.0f / fmaxf(sqrtf(ss), 1e-12f);
    out[(size_t)blk * CDIM + c] = v * inv;
    if (threadIdx.x == 0) rs[blk] = ss * inv * inv;
}

// ---------------- K5: global L2 normalize per image (in place) --------------
// grid 256 = (n, 8), 256 threads
__global__ __launch_bounds__(256) void k_gnorm(const float* __restrict__ rs,
                                               float* __restrict__ out) {
    int n = blockIdx.x >> 3, j = blockIdx.x & 7;
    float ss = 0.f;
    for (int k = 0; k < KCL; k++) ss += rs[n * KCL + k];
    float g = 1.0f / fmaxf(sqrtf(ss), 1e-12f);
    size_t base = (size_t)n * (KCL * CDIM) + j * 2048 + threadIdx.x;
    for (int i = 0; i < 8; i++) out[base + i * 256] *= g;
}

extern "C" void kernel_launch(void* const* d_in, const int* in_sizes, int n_in,
                              void* d_out, int out_size, void* d_ws, size_t ws_size,
                              hipStream_t stream) {
    const float* x    = (const float*)d_in[0];   // [32][256][64][64]
    const float* w    = (const float*)d_in[1];   // [64][256]
    const float* b    = (const float*)d_in[2];   // [64]
    const float* cent = (const float*)d_in[3];   // [64][256]
    float* out = (float*)d_out;

    float* ws = (float*)d_ws;
    float* wT        = ws;                        // 16384
    float* inv_norm  = wT + 16384;                // 131072
    float* aT        = inv_norm + 131072;         // 32*4096*64 = 8388608
    float* vlad_part = aT + 8388608;              // 512*64*256 = 8388608
    float* asum_part = vlad_part + 8388608;       // 512*64 = 32768
    float* rs        = asum_part + 32768;         // 2048

    k_wt<<<64, 256, 0, stream>>>(w, wT);
    k_logits<<<512, 512, 0, stream>>>(x, wT, b, aT, inv_norm, asum_part);
    k_vlad<<<512, 512, 0, stream>>>(x, inv_norm, aT, vlad_part);
    k_combine<<<2048, 256, 0, stream>>>(vlad_part, asum_part, cent, out, rs);
    k_gnorm<<<256, 256, 0, stream>>>(rs, out);
}